// Round 4
// baseline (587.018 us; speedup 1.0000x reference)
//
#include <hip/hip_runtime.h>

#define NEG_SLOPE 0.2f
#define D_FIXED 512
#define ROWS_PER_WAVE 4

// Fixed-point scales for the packed 64-bit atomic accumulator.
// low 32 bits  : denominator (always-positive, monotone; worst case ~3000*2^19=1.6e9 < 2^32)
// high 32 bits : numerator, signed two's complement (carry-isolated from low word)
#define DEN_SCALE 524288.0f     // 2^19
#define NUM_SCALE 32768.0f      // 2^15
#define INV_DEN_SCALE (1.0f / 524288.0f)
#define INV_NUM_SCALE (1.0f / 32768.0f)

// -------- Kernel 1: x = F @ W, 4 rows per wave, W staged in LDS --------
// Per wave: 8 independent coalesced dwordx4 F loads in flight (4x MLP of the
// 1-row version), then 4 parallel xor-butterfly reductions (latency paid once).
__global__ __launch_bounds__(256) void gemv_rowdot(const float* __restrict__ F,
                                                   const float* __restrict__ W,
                                                   float* __restrict__ x, int n) {
    __shared__ float4 wlds[D_FIXED / 4];          // 2 KB
    int t = threadIdx.x;
    if (t < D_FIXED / 4) wlds[t] = ((const float4*)W)[t];
    __syncthreads();

    int lane = t & 63;
    int rowBase = (blockIdx.x * 4 + (t >> 6)) * ROWS_PER_WAVE;   // 16 rows / block

    float4 a[ROWS_PER_WAVE][2];
    #pragma unroll
    for (int r = 0; r < ROWS_PER_WAVE; ++r) {
        int row = rowBase + r;
        if (row < n) {
            const float4* f4 = (const float4*)(F + (size_t)row * D_FIXED);
            a[r][0] = f4[lane];                   // coalesced 1 KB wave access
            a[r][1] = f4[lane + 64];
        } else {
            a[r][0] = make_float4(0.f, 0.f, 0.f, 0.f);
            a[r][1] = make_float4(0.f, 0.f, 0.f, 0.f);
        }
    }
    float4 w0 = wlds[lane], w1 = wlds[lane + 64];

    float s[ROWS_PER_WAVE];
    #pragma unroll
    for (int r = 0; r < ROWS_PER_WAVE; ++r) {
        s[r] = a[r][0].x * w0.x + a[r][0].y * w0.y + a[r][0].z * w0.z + a[r][0].w * w0.w
             + a[r][1].x * w1.x + a[r][1].y * w1.y + a[r][1].z * w1.z + a[r][1].w * w1.w;
    }

    #pragma unroll
    for (int off = 32; off; off >>= 1) {
        #pragma unroll
        for (int r = 0; r < ROWS_PER_WAVE; ++r)
            s[r] += __shfl_xor(s[r], off, 64);    // 4 independent chains, latency overlaps
    }

    if (lane == 0 && rowBase + 3 < n) {
        *(float4*)(x + rowBase) = make_float4(s[0], s[1], s[2], s[3]);
    } else if (lane == 0) {
        for (int r = 0; r < ROWS_PER_WAVE && rowBase + r < n; ++r) x[rowBase + r] = s[r];
    }
}

// -------- Kernel 2: per-edge exp(lrelu) -> ONE u64 fixed-point atomic per edge ----
__global__ void edge_accum(const int* __restrict__ src, const int* __restrict__ dst,
                           const float* __restrict__ x,
                           const float* __restrict__ att_src_p,
                           const float* __restrict__ att_dst_p,
                           unsigned long long* __restrict__ acc, int nedges) {
    int i = blockIdx.x * blockDim.x + threadIdx.x;
    if (i >= nedges) return;
    int s = src[i], d = dst[i];
    float as = *att_src_p, ad = *att_dst_p;
    float xs = x[s], xd = x[d];
    float v = xs * as + xd * ad;
    float logit = v > 0.f ? v : NEG_SLOPE * v;
    float e = __expf(logit);               // logits are O(1); fast exp is exact enough
    unsigned int den_fx = (unsigned int)__float2int_rn(e * DEN_SCALE);
    int          num_fx = __float2int_rn(e * xs * NUM_SCALE);
    unsigned long long upd =
        ((unsigned long long)(unsigned int)num_fx << 32) | (unsigned long long)den_fx;
    atomicAdd(&acc[d], upd);
}

// -------- Kernel 3: out = (num + e_self*x) / (den + e_self) + bias --------
__global__ void finalize(const unsigned long long* __restrict__ acc,
                         const float* __restrict__ x,
                         const float* __restrict__ att_src_p,
                         const float* __restrict__ att_dst_p,
                         const float* __restrict__ bias, float* __restrict__ out, int n) {
    int i = blockIdx.x * blockDim.x + threadIdx.x;
    if (i >= n) return;
    float xi = x[i];
    float v = xi * (*att_src_p + *att_dst_p);      // self-loop logit
    float logit = v > 0.f ? v : NEG_SLOPE * v;
    float es = __expf(logit);
    unsigned long long a = acc[i];
    float num = (float)(int)(a >> 32) * INV_NUM_SCALE;
    float den = (float)(unsigned int)(a & 0xFFFFFFFFull) * INV_DEN_SCALE;
    out[i] = (num + es * xi) / (den + es) + *bias;
}

extern "C" void kernel_launch(void* const* d_in, const int* in_sizes, int n_in,
                              void* d_out, int out_size, void* d_ws, size_t ws_size,
                              hipStream_t stream) {
    const float* F       = (const float*)d_in[0];
    const int*   ei      = (const int*)d_in[1];
    const float* W       = (const float*)d_in[2];
    const float* att_src = (const float*)d_in[3];
    const float* att_dst = (const float*)d_in[4];
    const float* bias    = (const float*)d_in[5];
    float* out = (float*)d_out;

    int d = in_sizes[2];              // 512
    int n = in_sizes[0] / d;          // 100000
    int e = in_sizes[1] / 2;          // 6400000

    float* x = (float*)d_ws;                                // [n] floats
    unsigned long long* acc = (unsigned long long*)(x + n); // [n] u64 (n*4 is 8B-aligned)

    // ws is re-poisoned 0xAA before every timed launch -> zero the accumulators
    (void)hipMemsetAsync(acc, 0, (size_t)n * sizeof(unsigned long long), stream);

    int rowsPerBlock = 4 * ROWS_PER_WAVE;   // 16
    gemv_rowdot<<<(n + rowsPerBlock - 1) / rowsPerBlock, 256, 0, stream>>>(F, W, x, n);

    edge_accum<<<(e + 255) / 256, 256, 0, stream>>>(ei, ei + e, x, att_src, att_dst,
                                                    acc, e);

    finalize<<<(n + 255) / 256, 256, 0, stream>>>(acc, x, att_src, att_dst, bias, out, n);
}

// Round 5
// 582.975 us; speedup vs baseline: 1.0069x; 1.0069x over previous
//
#include <hip/hip_runtime.h>

#define NEG_SLOPE 0.2f
#define D_FIXED 512

// Fixed-point scales for the packed 64-bit atomic accumulator.
// low 32 bits  : denominator (always-positive, monotone; worst case ~3000*2^19=1.6e9 < 2^32)
// high 32 bits : numerator, signed two's complement (carry-isolated from low word)
#define DEN_SCALE 524288.0f     // 2^19
#define NUM_SCALE 32768.0f      // 2^15
#define INV_DEN_SCALE (1.0f / 524288.0f)
#define INV_NUM_SCALE (1.0f / 32768.0f)

// -------- Kernel 1: persistent x = F @ W, 4 rows per wave-iteration --------
// 2048 resident blocks grid-stride over rows: no dispatch churn, loads of the
// next 4 rows pipeline against the current butterfly. Also zeroes acc (fused
// memset). W lives in registers (one L2-hot load per wave).
__global__ __launch_bounds__(256) void gemv_rowdot(const float* __restrict__ F,
                                                   const float* __restrict__ W,
                                                   float* __restrict__ x,
                                                   unsigned long long* __restrict__ acc,
                                                   int n) {
    int tid = blockIdx.x * blockDim.x + threadIdx.x;
    int nthreads = gridDim.x * blockDim.x;

    // fused accumulator zeroing (replaces hipMemsetAsync dispatch)
    for (int i = tid; i < n; i += nthreads) acc[i] = 0ull;

    int lane = threadIdx.x & 63;
    int wave = tid >> 6;
    int nwaves = nthreads >> 6;

    const float4* w4 = (const float4*)W;
    float4 w0 = w4[lane], w1 = w4[lane + 64];

    for (int rowBase = wave * 4; rowBase < n; rowBase += nwaves * 4) {
        float4 a[4][2];
        #pragma unroll
        for (int r = 0; r < 4; ++r) {
            int row = rowBase + r;
            if (row >= n) row = n - 1;                    // clamp (dup load, store guarded)
            const float4* f4 = (const float4*)(F + (size_t)row * D_FIXED);
            a[r][0] = f4[lane];                            // coalesced 1 KB wave access
            a[r][1] = f4[lane + 64];
        }
        float s[4];
        #pragma unroll
        for (int r = 0; r < 4; ++r) {
            s[r] = a[r][0].x * w0.x + a[r][0].y * w0.y + a[r][0].z * w0.z + a[r][0].w * w0.w
                 + a[r][1].x * w1.x + a[r][1].y * w1.y + a[r][1].z * w1.z + a[r][1].w * w1.w;
        }
        #pragma unroll
        for (int off = 32; off; off >>= 1) {
            #pragma unroll
            for (int r = 0; r < 4; ++r)
                s[r] += __shfl_xor(s[r], off, 64);         // 4 independent chains
        }
        if (lane == 0) {
            if (rowBase + 3 < n) {
                *(float4*)(x + rowBase) = make_float4(s[0], s[1], s[2], s[3]);
            } else {
                for (int r = 0; r < 4 && rowBase + r < n; ++r) x[rowBase + r] = s[r];
            }
        }
    }
}

// -------- Kernel 2: per-edge exp(lrelu) -> ONE u64 fixed-point atomic per edge ----
__global__ void edge_accum(const int* __restrict__ src, const int* __restrict__ dst,
                           const float* __restrict__ x,
                           const float* __restrict__ att_src_p,
                           const float* __restrict__ att_dst_p,
                           unsigned long long* __restrict__ acc, int nedges) {
    int i = blockIdx.x * blockDim.x + threadIdx.x;
    if (i >= nedges) return;
    int s = src[i], d = dst[i];
    float as = *att_src_p, ad = *att_dst_p;
    float xs = x[s], xd = x[d];
    float v = xs * as + xd * ad;
    float logit = v > 0.f ? v : NEG_SLOPE * v;
    float e = __expf(logit);               // logits are O(1); fast exp is exact enough
    unsigned int den_fx = (unsigned int)__float2int_rn(e * DEN_SCALE);
    int          num_fx = __float2int_rn(e * xs * NUM_SCALE);
    unsigned long long upd =
        ((unsigned long long)(unsigned int)num_fx << 32) | (unsigned long long)den_fx;
    atomicAdd(&acc[d], upd);
}

// -------- Kernel 3: out = (num + e_self*x) / (den + e_self) + bias --------
__global__ void finalize(const unsigned long long* __restrict__ acc,
                         const float* __restrict__ x,
                         const float* __restrict__ att_src_p,
                         const float* __restrict__ att_dst_p,
                         const float* __restrict__ bias, float* __restrict__ out, int n) {
    int i = blockIdx.x * blockDim.x + threadIdx.x;
    if (i >= n) return;
    float xi = x[i];
    float v = xi * (*att_src_p + *att_dst_p);      // self-loop logit
    float logit = v > 0.f ? v : NEG_SLOPE * v;
    float es = __expf(logit);
    unsigned long long a = acc[i];
    float num = (float)(int)(a >> 32) * INV_NUM_SCALE;
    float den = (float)(unsigned int)(a & 0xFFFFFFFFull) * INV_DEN_SCALE;
    out[i] = (num + es * xi) / (den + es) + *bias;
}

extern "C" void kernel_launch(void* const* d_in, const int* in_sizes, int n_in,
                              void* d_out, int out_size, void* d_ws, size_t ws_size,
                              hipStream_t stream) {
    const float* F       = (const float*)d_in[0];
    const int*   ei      = (const int*)d_in[1];
    const float* W       = (const float*)d_in[2];
    const float* att_src = (const float*)d_in[3];
    const float* att_dst = (const float*)d_in[4];
    const float* bias    = (const float*)d_in[5];
    float* out = (float*)d_out;

    int d = in_sizes[2];              // 512
    int n = in_sizes[0] / d;          // 100000
    int e = in_sizes[1] / 2;          // 6400000

    float* x = (float*)d_ws;                                // [n] floats
    unsigned long long* acc = (unsigned long long*)(x + n); // [n] u64 (n*4 is 8B-aligned)

    // persistent gemv: 2048 blocks (~8/CU), zeroes acc internally
    gemv_rowdot<<<2048, 256, 0, stream>>>(F, W, x, acc, n);

    edge_accum<<<(e + 255) / 256, 256, 0, stream>>>(ei, ei + e, x, att_src, att_dst,
                                                    acc, e);

    finalize<<<(n + 255) / 256, 256, 0, stream>>>(acc, x, att_src, att_dst, bias, out, n);
}

// Round 6
// 580.612 us; speedup vs baseline: 1.0110x; 1.0041x over previous
//
#include <hip/hip_runtime.h>

#define NEG_SLOPE 0.2f
#define D_FIXED 512
#define NXCD 8

// Fixed-point scales for the packed 64-bit atomic accumulator.
// low 32 bits  : denominator (always-positive, monotone; worst case ~3000*2^19=1.6e9 < 2^32)
// high 32 bits : numerator, signed two's complement (carry-isolated from low word)
#define DEN_SCALE 524288.0f     // 2^19
#define NUM_SCALE 32768.0f      // 2^15
#define INV_DEN_SCALE (1.0f / 524288.0f)
#define INV_NUM_SCALE (1.0f / 32768.0f)

// -------- Kernel 1: persistent x = F @ W + zero the 8 per-XCD partials --------
__global__ __launch_bounds__(256) void gemv_rowdot(const float* __restrict__ F,
                                                   const float* __restrict__ W,
                                                   float* __restrict__ x,
                                                   unsigned long long* __restrict__ acc,
                                                   int n) {
    int tid = blockIdx.x * blockDim.x + threadIdx.x;
    int nthreads = gridDim.x * blockDim.x;

    // fused zeroing of all 8 per-XCD partial accumulators (written via local TCC,
    // flushed at kernel end -> visible to edge_accum)
    for (int i = tid; i < n * NXCD; i += nthreads) acc[i] = 0ull;

    int lane = threadIdx.x & 63;
    int wave = tid >> 6;
    int nwaves = nthreads >> 6;

    const float4* w4 = (const float4*)W;
    float4 w0 = w4[lane], w1 = w4[lane + 64];

    for (int rowBase = wave * 4; rowBase < n; rowBase += nwaves * 4) {
        float4 a[4][2];
        #pragma unroll
        for (int r = 0; r < 4; ++r) {
            int row = rowBase + r;
            if (row >= n) row = n - 1;                    // clamp (dup load, store guarded)
            const float4* f4 = (const float4*)(F + (size_t)row * D_FIXED);
            a[r][0] = f4[lane];                            // coalesced 1 KB wave access
            a[r][1] = f4[lane + 64];
        }
        float s[4];
        #pragma unroll
        for (int r = 0; r < 4; ++r) {
            s[r] = a[r][0].x * w0.x + a[r][0].y * w0.y + a[r][0].z * w0.z + a[r][0].w * w0.w
                 + a[r][1].x * w1.x + a[r][1].y * w1.y + a[r][1].z * w1.z + a[r][1].w * w1.w;
        }
        #pragma unroll
        for (int off = 32; off; off >>= 1) {
            #pragma unroll
            for (int r = 0; r < 4; ++r)
                s[r] += __shfl_xor(s[r], off, 64);         // 4 independent chains
        }
        if (lane == 0) {
            if (rowBase + 3 < n) {
                *(float4*)(x + rowBase) = make_float4(s[0], s[1], s[2], s[3]);
            } else {
                for (int r = 0; r < 4 && rowBase + r < n; ++r) x[rowBase + r] = s[r];
            }
        }
    }
}

// -------- Kernel 2: per-edge exp(lrelu) -> u64 atomic into THIS XCD's partial ----
// Workgroup-scope atomic drops sc1 -> RMW executes in the local TCC (L2).
// Correct because partial[xcc] is only ever accessed from XCD xcc; the end-of-
// kernel release flush makes the partials visible to finalize.
__global__ void edge_accum(const int* __restrict__ src, const int* __restrict__ dst,
                           const float* __restrict__ x,
                           const float* __restrict__ att_src_p,
                           const float* __restrict__ att_dst_p,
                           unsigned long long* __restrict__ acc,
                           int nedges, int nnodes) {
    unsigned int xcc;
    asm volatile("s_getreg_b32 %0, hwreg(HW_REG_XCC_ID)" : "=s"(xcc));
    unsigned long long* myacc = acc + (size_t)(xcc & (NXCD - 1)) * nnodes;

    int i = blockIdx.x * blockDim.x + threadIdx.x;
    if (i >= nedges) return;
    int s = src[i], d = dst[i];
    float as = *att_src_p, ad = *att_dst_p;
    float xs = x[s], xd = x[d];
    float v = xs * as + xd * ad;
    float logit = v > 0.f ? v : NEG_SLOPE * v;
    float e = __expf(logit);               // logits are O(1); fast exp is exact enough
    unsigned int den_fx = (unsigned int)__float2int_rn(e * DEN_SCALE);
    int          num_fx = __float2int_rn(e * xs * NUM_SCALE);
    unsigned long long upd =
        ((unsigned long long)(unsigned int)num_fx << 32) | (unsigned long long)den_fx;
    __hip_atomic_fetch_add(&myacc[d], upd, __ATOMIC_RELAXED, __HIP_MEMORY_SCOPE_WORKGROUP);
}

// -------- Kernel 3: out = (Σ_xcd num + e_self*x) / (Σ_xcd den + e_self) + bias ---
__global__ void finalize(const unsigned long long* __restrict__ acc,
                         const float* __restrict__ x,
                         const float* __restrict__ att_src_p,
                         const float* __restrict__ att_dst_p,
                         const float* __restrict__ bias, float* __restrict__ out,
                         int n) {
    int i = blockIdx.x * blockDim.x + threadIdx.x;
    if (i >= n) return;
    long long num_fx = 0;
    unsigned long long den_fx = 0;
    #pragma unroll
    for (int k = 0; k < NXCD; ++k) {
        unsigned long long a = acc[(size_t)k * n + i];
        num_fx += (long long)(int)(a >> 32);
        den_fx += (a & 0xFFFFFFFFull);
    }
    float num = (float)num_fx * INV_NUM_SCALE;
    float den = (float)den_fx * INV_DEN_SCALE;
    float xi = x[i];
    float v = xi * (*att_src_p + *att_dst_p);      // self-loop logit
    float logit = v > 0.f ? v : NEG_SLOPE * v;
    float es = __expf(logit);
    out[i] = (num + es * xi) / (den + es) + *bias;
}

extern "C" void kernel_launch(void* const* d_in, const int* in_sizes, int n_in,
                              void* d_out, int out_size, void* d_ws, size_t ws_size,
                              hipStream_t stream) {
    const float* F       = (const float*)d_in[0];
    const int*   ei      = (const int*)d_in[1];
    const float* W       = (const float*)d_in[2];
    const float* att_src = (const float*)d_in[3];
    const float* att_dst = (const float*)d_in[4];
    const float* bias    = (const float*)d_in[5];
    float* out = (float*)d_out;

    int d = in_sizes[2];              // 512
    int n = in_sizes[0] / d;          // 100000
    int e = in_sizes[1] / 2;          // 6400000

    float* x = (float*)d_ws;                                // [n] floats (400000 B, 64-aligned)
    unsigned long long* acc = (unsigned long long*)(x + n); // [8][n] u64 partials (6.4 MB)

    // persistent gemv: 2048 blocks (~8/CU), zeroes the partials internally
    gemv_rowdot<<<2048, 256, 0, stream>>>(F, W, x, acc, n);

    edge_accum<<<(e + 255) / 256, 256, 0, stream>>>(ei, ei + e, x, att_src, att_dst,
                                                    acc, e, n);

    finalize<<<(n + 255) / 256, 256, 0, stream>>>(acc, x, att_src, att_dst, bias, out, n);
}